// Round 1
// baseline (36464.093 us; speedup 1.0000x reference)
//
#include <hip/hip_runtime.h>

#define NN 50000
#define EE 800000
#define DIN 128
#define DH 64
#define CC 4
#define LL 3

__device__ __forceinline__ float sigmoidf_(float x) {
    return __builtin_amdgcn_rcpf(1.0f + __expf(-x));
}

// ---------------- degree count (once per launch) ----------------
__global__ void cnt_kernel(const int* __restrict__ dst, float* __restrict__ cnt, int E) {
    int e = blockIdx.x * 256 + threadIdx.x;
    if (e < E) atomicAdd(&cnt[dst[e]], 1.0f);
}

// ---------------- mix_in: h[c][i][d] = x[i] @ W[:,c*64+d] ----------------
__global__ __launch_bounds__(256) void mix_in_kernel(
        const float* __restrict__ x,   // [N][128]
        const float* __restrict__ W,   // [128][256] (layer base)
        float* __restrict__ h,         // [C][N][64]
        int N) {
    __shared__ float xs[8][DIN];
    const int i0 = blockIdx.x * 8;
    const int tid = threadIdx.x;
    for (int t = tid; t < 8 * DIN; t += 256) {
        int j = t / DIN, k = t % DIN;
        int i = i0 + j;
        xs[j][k] = (i < N) ? x[(size_t)i * DIN + k] : 0.f;
    }
    __syncthreads();
    float acc[8] = {0.f, 0.f, 0.f, 0.f, 0.f, 0.f, 0.f, 0.f};
    for (int k = 0; k < DIN; ++k) {
        float w = W[k * (CC * DH) + tid];
        #pragma unroll
        for (int j = 0; j < 8; ++j) acc[j] += xs[j][k] * w;
    }
    const int c = tid >> 6, d = tid & 63;
    #pragma unroll
    for (int j = 0; j < 8; ++j) {
        int i = i0 + j;
        if (i < N) h[((size_t)c * N + i) * DH + d] = acc[j];
    }
}

// ---------------- edge kernel: one edge per lane ----------------
__global__ __launch_bounds__(256, 2) void edge_kernel(
    const float* __restrict__ h,     // [C][N][64]
    const float* __restrict__ pos,   // [N][3]
    const int* __restrict__ src,
    const int* __restrict__ dst,
    const float* __restrict__ ew1,   // [C][129][64] (layer base)
    const float* __restrict__ eb1,   // [C][64]
    const float* __restrict__ ew2,   // [C][64][64]
    const float* __restrict__ eb2,   // [C][64]
    const float* __restrict__ gw,    // [C][64]
    const float* __restrict__ gb,    // [C]
    const float* __restrict__ pw1,   // [C][64][64]
    const float* __restrict__ pb1,   // [C][64]
    const float* __restrict__ pw2,   // [C][64]
    float* __restrict__ agg,         // [C][N][64]
    float* __restrict__ pos_acc,     // [N][3]
    int E, int N)
{
    const int c = blockIdx.y;
    const int e = blockIdx.x * 256 + threadIdx.x;
    if (e >= E) return;
    const int s = src[e];
    const int t = dst[e];

    const float rx = pos[s * 3 + 0] - pos[t * 3 + 0];
    const float ry = pos[s * 3 + 1] - pos[t * 3 + 1];
    const float rz = pos[s * 3 + 2] - pos[t * 3 + 2];
    const float d2 = rx * rx + ry * ry + rz * rz;

    const float* W1  = ew1 + (size_t)c * (2 * DH + 1) * DH;
    const float* B1  = eb1 + (size_t)c * DH;
    const float* W2  = ew2 + (size_t)c * DH * DH;
    const float* B2  = eb2 + (size_t)c * DH;
    const float* GW  = gw  + (size_t)c * DH;
    const float  GB  = gb[c];
    const float* PW1 = pw1 + (size_t)c * DH * DH;
    const float* PB1 = pb1 + (size_t)c * DH;
    const float* PW2 = pw2 + (size_t)c * DH;

    const float* hsrow = h + ((size_t)c * N + s) * DH;
    const float* hdrow = h + ((size_t)c * N + t) * DH;

    // ---- m1 = silu([h_s, h_d, d2] @ W1 + B1) ----
    float m1[DH];
    #pragma unroll
    for (int d = 0; d < DH; ++d) m1[d] = B1[d];

    #pragma unroll 4
    for (int k = 0; k < DH; ++k) {
        const float xv = hsrow[k];
        const float* w = W1 + (size_t)k * DH;
        #pragma unroll
        for (int d = 0; d < DH; ++d) m1[d] += xv * w[d];
    }
    #pragma unroll 4
    for (int k = 0; k < DH; ++k) {
        const float xv = hdrow[k];
        const float* w = W1 + (size_t)(DH + k) * DH;
        #pragma unroll
        for (int d = 0; d < DH; ++d) m1[d] += xv * w[d];
    }
    {
        const float* w = W1 + (size_t)(2 * DH) * DH;
        #pragma unroll
        for (int d = 0; d < DH; ++d) m1[d] += d2 * w[d];
    }
    #pragma unroll
    for (int d = 0; d < DH; ++d) m1[d] = m1[d] * sigmoidf_(m1[d]);

    // ---- m2 = silu(m1 @ W2 + B2) ----
    float m2[DH];
    #pragma unroll
    for (int d = 0; d < DH; ++d) m2[d] = B2[d];
    #pragma unroll
    for (int k = 0; k < DH; ++k) {
        const float xv = m1[k];
        const float* w = W2 + (size_t)k * DH;
        #pragma unroll
        for (int d = 0; d < DH; ++d) m2[d] += xv * w[d];
    }
    #pragma unroll
    for (int d = 0; d < DH; ++d) m2[d] = m2[d] * sigmoidf_(m2[d]);

    // ---- gate ----
    float g0 = 0.f, g1 = 0.f, g2 = 0.f, g3 = 0.f;
    #pragma unroll
    for (int k = 0; k < DH; k += 4) {
        g0 += m2[k + 0] * GW[k + 0];
        g1 += m2[k + 1] * GW[k + 1];
        g2 += m2[k + 2] * GW[k + 2];
        g3 += m2[k + 3] * GW[k + 3];
    }
    const float gate = sigmoidf_(GB + ((g0 + g1) + (g2 + g3)));
    #pragma unroll
    for (int d = 0; d < DH; ++d) m2[d] *= gate;

    // ---- q = silu(m2 @ PW1 + PB1); p = q @ PW2 ----  (reuse m1 as q)
    #pragma unroll
    for (int d = 0; d < DH; ++d) m1[d] = PB1[d];
    #pragma unroll
    for (int k = 0; k < DH; ++k) {
        const float xv = m2[k];
        const float* w = PW1 + (size_t)k * DH;
        #pragma unroll
        for (int d = 0; d < DH; ++d) m1[d] += xv * w[d];
    }
    float p0 = 0.f, p1 = 0.f, p2 = 0.f, p3 = 0.f;
    #pragma unroll
    for (int k = 0; k < DH; k += 4) {
        p0 += (m1[k + 0] * sigmoidf_(m1[k + 0])) * PW2[k + 0];
        p1 += (m1[k + 1] * sigmoidf_(m1[k + 1])) * PW2[k + 1];
        p2 += (m1[k + 2] * sigmoidf_(m1[k + 2])) * PW2[k + 2];
        p3 += (m1[k + 3] * sigmoidf_(m1[k + 3])) * PW2[k + 3];
    }
    const float p = (p0 + p1) + (p2 + p3);

    // ---- coordinate update contribution ----
    const float tx = fminf(fmaxf(rx * p, -2.0f), 2.0f);
    const float ty = fminf(fmaxf(ry * p, -2.0f), 2.0f);
    const float tz = fminf(fmaxf(rz * p, -2.0f), 2.0f);
    atomicAdd(&pos_acc[t * 3 + 0], tx);
    atomicAdd(&pos_acc[t * 3 + 1], ty);
    atomicAdd(&pos_acc[t * 3 + 2], tz);

    // ---- aggregate gated messages ----
    float* arow = agg + ((size_t)c * N + t) * DH;
    #pragma unroll
    for (int d = 0; d < DH; ++d) atomicAdd(arow + d, m2[d]);
}

// ---------------- node update: h_out = [h, agg] @ nw + nb  (in-place over agg) ----------------
__global__ __launch_bounds__(256) void node_kernel(
        const float* __restrict__ h,   // [C][N][64]
        float* __restrict__ agg,       // in: agg, out: h_out  [C][N][64]
        const float* __restrict__ nw,  // [C][128][64] (layer base)
        const float* __restrict__ nb,  // [C][64]
        int N) {
    const int c = blockIdx.y;
    const int wave = threadIdx.x >> 6, lane = threadIdx.x & 63;
    const int i = blockIdx.x * 4 + wave;
    if (i >= N) return;
    const float* hrow = h + ((size_t)c * N + i) * DH;
    float* arow = agg + ((size_t)c * N + i) * DH;
    const float* W = nw + (size_t)c * (2 * DH) * DH;
    float acc = nb[(size_t)c * DH + lane];
    #pragma unroll 8
    for (int k = 0; k < DH; ++k) acc += hrow[k] * W[(size_t)k * DH + lane];
    #pragma unroll 8
    for (int k = 0; k < DH; ++k) acc += arow[k] * W[(size_t)(DH + k) * DH + lane];
    arow[lane] = acc;
}

// ---------------- mix_out: x += h_out_flat @ W ----------------
__global__ __launch_bounds__(256) void mix_out_kernel(
        const float* __restrict__ hout, // [C][N][64]
        const float* __restrict__ W,    // [256][128] (layer base)
        float* __restrict__ x,          // [N][128]
        int N) {
    __shared__ float hs[8][CC * DH];
    const int i0 = blockIdx.x * 8;
    const int tid = threadIdx.x;
    for (int t = tid; t < 8 * CC * DH; t += 256) {
        int j = t >> 8, cd = t & 255;
        int c = cd >> 6, d = cd & 63;
        int i = i0 + j;
        hs[j][cd] = (i < N) ? hout[((size_t)c * N + i) * DH + d] : 0.f;
    }
    __syncthreads();
    const int o = tid & 127, g = tid >> 7;
    float acc[4] = {0.f, 0.f, 0.f, 0.f};
    for (int cd = 0; cd < CC * DH; ++cd) {
        float w = W[(size_t)cd * DIN + o];
        #pragma unroll
        for (int j = 0; j < 4; ++j) acc[j] += hs[g * 4 + j][cd] * w;
    }
    #pragma unroll
    for (int j = 0; j < 4; ++j) {
        int i = i0 + g * 4 + j;
        if (i < N) x[(size_t)i * DIN + o] += acc[j];
    }
}

// ---------------- pos finalize: pos += pos_acc / (C * max(cnt,1)) ----------------
__global__ void pos_fin_kernel(float* __restrict__ pos, const float* __restrict__ pos_acc,
                               const float* __restrict__ cnt, int N) {
    int i = blockIdx.x * 256 + threadIdx.x;
    if (i < N) {
        float inv = 1.0f / ((float)CC * fmaxf(cnt[i], 1.0f));
        pos[i * 3 + 0] += pos_acc[i * 3 + 0] * inv;
        pos[i * 3 + 1] += pos_acc[i * 3 + 1] * inv;
        pos[i * 3 + 2] += pos_acc[i * 3 + 2] * inv;
    }
}

extern "C" void kernel_launch(void* const* d_in, const int* in_sizes, int n_in,
                              void* d_out, int out_size, void* d_ws, size_t ws_size,
                              hipStream_t stream) {
    const float* x         = (const float*)d_in[0];
    const float* pos       = (const float*)d_in[1];
    const int*   ei        = (const int*)d_in[2];
    const float* mix_in_w  = (const float*)d_in[3];
    const float* mix_out_w = (const float*)d_in[4];
    const float* ew1       = (const float*)d_in[5];
    const float* eb1       = (const float*)d_in[6];
    const float* ew2       = (const float*)d_in[7];
    const float* eb2       = (const float*)d_in[8];
    const float* gw        = (const float*)d_in[9];
    const float* gb        = (const float*)d_in[10];
    const float* nw        = (const float*)d_in[11];
    const float* nb        = (const float*)d_in[12];
    const float* pw1       = (const float*)d_in[13];
    const float* pb1       = (const float*)d_in[14];
    const float* pw2       = (const float*)d_in[15];

    const int* src = ei;
    const int* dst = ei + EE;

    float* xout    = (float*)d_out;                 // [N][128]
    float* pos_out = xout + (size_t)NN * DIN;       // [N][3]

    float* hbuf    = (float*)d_ws;                  // C*N*64
    float* aggb    = hbuf + (size_t)CC * NN * DH;   // C*N*64
    float* pos_cur = aggb + (size_t)CC * NN * DH;   // N*3
    float* pos_acc = pos_cur + (size_t)NN * 3;      // N*3
    float* cntb    = pos_acc + (size_t)NN * 3;      // N

    hipMemcpyAsync(xout, x, sizeof(float) * NN * DIN, hipMemcpyDeviceToDevice, stream);
    hipMemcpyAsync(pos_cur, pos, sizeof(float) * NN * 3, hipMemcpyDeviceToDevice, stream);
    hipMemsetAsync(cntb, 0, sizeof(float) * NN, stream);
    cnt_kernel<<<(EE + 255) / 256, 256, 0, stream>>>(dst, cntb, EE);

    for (int l = 0; l < LL; ++l) {
        hipMemsetAsync(aggb, 0, sizeof(float) * CC * NN * DH, stream);
        hipMemsetAsync(pos_acc, 0, sizeof(float) * NN * 3, stream);

        mix_in_kernel<<<(NN + 7) / 8, 256, 0, stream>>>(
            xout, mix_in_w + (size_t)l * DIN * CC * DH, hbuf, NN);

        edge_kernel<<<dim3((EE + 255) / 256, CC), 256, 0, stream>>>(
            hbuf, pos_cur, src, dst,
            ew1 + (size_t)l * CC * (2 * DH + 1) * DH,
            eb1 + (size_t)l * CC * DH,
            ew2 + (size_t)l * CC * DH * DH,
            eb2 + (size_t)l * CC * DH,
            gw  + (size_t)l * CC * DH,
            gb  + (size_t)l * CC,
            pw1 + (size_t)l * CC * DH * DH,
            pb1 + (size_t)l * CC * DH,
            pw2 + (size_t)l * CC * DH,
            aggb, pos_acc, EE, NN);

        node_kernel<<<dim3((NN + 3) / 4, CC), 256, 0, stream>>>(
            hbuf, aggb,
            nw + (size_t)l * CC * 2 * DH * DH,
            nb + (size_t)l * CC * DH, NN);

        mix_out_kernel<<<(NN + 7) / 8, 256, 0, stream>>>(
            aggb, mix_out_w + (size_t)l * CC * DH * DIN, xout, NN);

        pos_fin_kernel<<<(NN + 255) / 256, 256, 0, stream>>>(pos_cur, pos_acc, cntb, NN);
    }

    hipMemcpyAsync(pos_out, pos_cur, sizeof(float) * NN * 3, hipMemcpyDeviceToDevice, stream);
}